// Round 2
// baseline (2952.280 us; speedup 1.0000x reference)
//
#include <hip/hip_runtime.h>
#include <math.h>

// Problem constants
#define BB    8192
#define NN    512
#define KKN   8
#define HH    1024
#define OUTD  (NN * (2 * KKN + 1))   // 8704
#define CHUNK 512                     // batch rows per GEMM3+spline chunk

// Workspace budget: x1 (32 MiB) + x2 (32 MiB) = 64 MiB total.
// net is processed in CHUNK-row chunks; chunk buffer (17 MiB) aliases x1,
// which is dead after GEMM2 (stream order serializes all hazards).

// ---------------------------------------------------------------------------
// GEMM: C = tanh(op(A) @ W + bias)
//   A: M x Kdim row-major, leading dim lda (op = optional -0.5)
//   W: Kdim x N_ row-major;  C: M x N_ row-major, leading dim ldc
// Tiles: 64x64, BK=16, 256 threads, 4x4 per thread. All dims are exact
// multiples of the tile -> no guards.
// ---------------------------------------------------------------------------
template <bool SUB_HALF>
__global__ __launch_bounds__(256) void gemm_tanh(
    const float* __restrict__ A, int lda,
    const float* __restrict__ W, int N_,
    const float* __restrict__ bias,
    float* __restrict__ C, int ldc,
    int Kdim)
{
    const int BM = 64, BN = 64, BK = 16;
    __shared__ float sA[BK][BM + 4];
    __shared__ float sB[BK][BN + 4];

    const int t  = threadIdx.x;
    const int tx = t % 16;             // col group
    const int ty = t / 16;             // row group
    const int block_row = blockIdx.y * BM;
    const int block_col = blockIdx.x * BN;

    const int kA = t % 16, rA = t / 16;    // A tile: 64 rows x 16 k
    const int cB = t % 64, rB = t / 64;    // B tile: 16 k x 64 cols

    float acc[4][4] = {};

    for (int k0 = 0; k0 < Kdim; k0 += BK) {
#pragma unroll
        for (int i = 0; i < 4; i++) {
            float a = A[(size_t)(block_row + rA + 16 * i) * lda + (k0 + kA)];
            if (SUB_HALF) a -= 0.5f;
            sA[kA][rA + 16 * i] = a;
        }
#pragma unroll
        for (int i = 0; i < 4; i++) {
            sB[rB + 4 * i][cB] = W[(size_t)(k0 + rB + 4 * i) * N_ + (block_col + cB)];
        }
        __syncthreads();

#pragma unroll
        for (int kk = 0; kk < BK; kk++) {
            float a_frag[4], b_frag[4];
#pragma unroll
            for (int i = 0; i < 4; i++) a_frag[i] = sA[kk][ty * 4 + i];
#pragma unroll
            for (int j = 0; j < 4; j++) b_frag[j] = sB[kk][tx * 4 + j];
#pragma unroll
            for (int i = 0; i < 4; i++)
#pragma unroll
                for (int j = 0; j < 4; j++)
                    acc[i][j] += a_frag[i] * b_frag[j];
        }
        __syncthreads();
    }

#pragma unroll
    for (int i = 0; i < 4; i++) {
        const int r = block_row + ty * 4 + i;
#pragma unroll
        for (int j = 0; j < 4; j++) {
            const int c = block_col + tx * 4 + j;
            C[(size_t)r * ldc + c] = tanhf(acc[i][j] + bias[c]);
        }
    }
}

// ---------------------------------------------------------------------------
// Spline postprocess on one CHUNK of batch rows. All global pointers are
// pre-offset to the chunk; blockIdx.x is the LOCAL row (0..CHUNK-1).
// One thread per spline unit n (512 threads).
// ---------------------------------------------------------------------------
__global__ __launch_bounds__(512) void spline_post(
    const float* __restrict__ net,      // CHUNK x OUTD  (chunk buffer)
    const float* __restrict__ v_in,     // chunk rows x 2N
    const float* __restrict__ ld_in,    // chunk rows
    float* __restrict__ v_out,          // chunk rows x 2N
    float* __restrict__ ld_out)         // chunk rows
{
    const int b = blockIdx.x;
    const int n = threadIdx.x;          // 0..511

    const float* row = net + (size_t)b * OUTD + n * 17;
    float t17[17];
#pragma unroll
    for (int i = 0; i < 17; i++) t17[i] = row[i];

    // softmax over w_net = t17[9..16]
    float m = t17[9];
#pragma unroll
    for (int i = 10; i < 17; i++) m = fmaxf(m, t17[i]);
    float wn[8], wsum = 0.f;
#pragma unroll
    for (int i = 0; i < 8; i++) { wn[i] = expf(t17[9 + i] - m); wsum += wn[i]; }
    const float winv = 1.f / wsum;
#pragma unroll
    for (int i = 0; i < 8; i++) wn[i] *= winv;

    // eh, denom, h_norm
    float eh[9];
#pragma unroll
    for (int i = 0; i < 9; i++) eh[i] = expf(t17[i]);
    float denom = 0.f;
#pragma unroll
    for (int k = 0; k < 8; k++) denom += 0.5f * wn[k] * (eh[k] + eh[k + 1]);
    const float dinv = 1.f / denom;
    float hn[9];
#pragma unroll
    for (int i = 0; i < 9; i++) hn[i] = eh[i] * dinv;

    // knots
    float kx[9], ky[9];
    kx[0] = 0.f; ky[0] = 0.f;
#pragma unroll
    for (int k = 0; k < 8; k++) {
        kx[k + 1] = kx[k] + wn[k];
        ky[k + 1] = ky[k] + 0.5f * wn[k] * (hn[k] + hn[k + 1]);
    }

    const float va = v_in[(size_t)b * (2 * NN) + NN + n];

    // segment: clip(count(kx < va) - 1, 0, K-1)
    int cnt = 0;
#pragma unroll
    for (int j = 0; j < 9; j++) cnt += (kx[j] < va) ? 1 : 0;
    int k = cnt - 1;
    k = k < 0 ? 0 : (k > KKN - 1 ? KKN - 1 : k);

    const float wseg = wn[k];
    const float hlo = hn[k], hhi = hn[k + 1];
    const float xlo = kx[k], ylo = ky[k];
    const float alpha = (va - xlo) / wseg;
    const float vact = ylo + alpha * hlo * wseg + 0.5f * alpha * alpha * (hhi - hlo) * wseg;
    const float lt = logf(hlo + alpha * (hhi - hlo));

    // outputs
    v_out[(size_t)b * (2 * NN) + n]      = v_in[(size_t)b * (2 * NN) + n];  // passive copy
    v_out[(size_t)b * (2 * NN) + NN + n] = vact;

    // block reduction of log terms
    __shared__ float red[512];
    red[n] = lt;
    __syncthreads();
#pragma unroll
    for (int s = 256; s > 0; s >>= 1) {
        if (n < s) red[n] += red[n + s];
        __syncthreads();
    }
    if (n == 0) ld_out[b] = ld_in[b] - red[0];
}

// ---------------------------------------------------------------------------
extern "C" void kernel_launch(void* const* d_in, const int* in_sizes, int n_in,
                              void* d_out, int out_size, void* d_ws, size_t ws_size,
                              hipStream_t stream)
{
    const float* v_in = (const float*)d_in[0];   // B x 2N
    const float* ld   = (const float*)d_in[1];   // B x 1
    const float* W1   = (const float*)d_in[2];   // N x H
    const float* b1   = (const float*)d_in[3];   // H
    const float* W2   = (const float*)d_in[4];   // H x H
    const float* b2   = (const float*)d_in[5];   // H
    const float* W3   = (const float*)d_in[6];   // H x OUTD
    const float* b3   = (const float*)d_in[7];   // OUTD

    float* out    = (float*)d_out;
    float* v_out  = out;                           // B*2N
    float* ld_out = out + (size_t)BB * (2 * NN);   // B

    // workspace: x1 | x2 (32 MiB each). chunkbuf aliases x1 (dead after GEMM2).
    float* x1 = (float*)d_ws;
    float* x2 = x1 + (size_t)BB * HH;
    float* chunkbuf = x1;   // CHUNK*OUTD floats = 17 MiB < 32 MiB

    dim3 blk(256);
    // GEMM1: x1 = tanh((v_passive - 0.5) @ W1 + b1)
    gemm_tanh<true><<<dim3(HH / 64, BB / 64), blk, 0, stream>>>(
        v_in, 2 * NN, W1, HH, b1, x1, HH, NN);
    // GEMM2: x2 = tanh(x1 @ W2 + b2)
    gemm_tanh<false><<<dim3(HH / 64, BB / 64), blk, 0, stream>>>(
        x1, HH, W2, HH, b2, x2, HH, HH);

    // GEMM3 + spline, chunked over batch rows (stream order serializes hazards)
    for (int c = 0; c < BB / CHUNK; ++c) {
        const float* xa = x2 + (size_t)c * CHUNK * HH;
        gemm_tanh<false><<<dim3(OUTD / 64, CHUNK / 64), blk, 0, stream>>>(
            xa, HH, W3, OUTD, b3, chunkbuf, OUTD, HH);
        spline_post<<<dim3(CHUNK), dim3(512), 0, stream>>>(
            chunkbuf,
            v_in  + (size_t)c * CHUNK * (2 * NN),
            ld    + (size_t)c * CHUNK,
            v_out + (size_t)c * CHUNK * (2 * NN),
            ld_out + (size_t)c * CHUNK);
    }
}

// Round 3
// 580.401 us; speedup vs baseline: 5.0866x; 5.0866x over previous
//
#include <hip/hip_runtime.h>
#include <math.h>

// Problem constants
#define BB    8192
#define NN    512
#define KKN   8
#define HH    1024
#define OUTD  (NN * (2 * KKN + 1))   // 8704
#define CHUNK 1024                    // batch rows per GEMM3+spline chunk

typedef unsigned short ushort_t;
typedef __bf16 bf16x8 __attribute__((ext_vector_type(8)));
typedef float  f32x4  __attribute__((ext_vector_type(4)));

// float -> bf16 with round-to-nearest-even
__device__ inline ushort_t f2bf(float f) {
    unsigned int u = __float_as_uint(f);
    unsigned int r = (u + 0x7fffu + ((u >> 16) & 1u)) >> 16;
    return (ushort_t)r;
}
__device__ inline float bf2f(ushort_t u) {
    return __uint_as_float(((unsigned int)u) << 16);
}

// ---------------------------------------------------------------------------
// conv_v: a0b[b][n] = bf16(v_in[b][n] - 0.5), n in [0,512). v_in rows are 1024.
// One thread per 2 elements (float2 load).
// ---------------------------------------------------------------------------
__global__ __launch_bounds__(256) void conv_v(
    const float* __restrict__ v_in, ushort_t* __restrict__ a0b)
{
    int t = blockIdx.x * 256 + threadIdx.x;          // 0 .. B*512/2-1
    int e0 = t * 2;
    int b = e0 >> 9;
    int n = e0 & 511;
    const float2 v = *(const float2*)(v_in + (size_t)b * (2 * NN) + n);
    ushort_t* o = a0b + (size_t)b * NN + n;
    o[0] = f2bf(v.x - 0.5f);
    o[1] = f2bf(v.y - 0.5f);
}

// ---------------------------------------------------------------------------
// transpose_cvt: W (Kd x Nd fp32, row-major) -> WT (Nd x Kd bf16, row-major)
// 32x32 tiles, block (32,8). Kd, Nd multiples of 32.
// ---------------------------------------------------------------------------
__global__ __launch_bounds__(256) void transpose_cvt(
    const float* __restrict__ W, ushort_t* __restrict__ WT, int Kd, int Nd)
{
    __shared__ float tile[32][33];
    const int bx = blockIdx.x * 32;   // n base
    const int by = blockIdx.y * 32;   // k base
    const int tx = threadIdx.x;       // 0..31
    const int ty = threadIdx.y;       // 0..7
#pragma unroll
    for (int i = 0; i < 32; i += 8)
        tile[ty + i][tx] = W[(size_t)(by + ty + i) * Nd + bx + tx];
    __syncthreads();
#pragma unroll
    for (int i = 0; i < 32; i += 8)
        WT[(size_t)(bx + ty + i) * Kd + by + tx] = f2bf(tile[tx][ty + i]);
}

// ---------------------------------------------------------------------------
// bf16 MFMA GEMM (m97 structure): C = bf16(tanh(A @ B + bias))
//   A : M x K bf16 row-major (K contiguous)
//   BT: N x K bf16 row-major (K contiguous)  == B transposed
//   C : M x N bf16 row-major
// 128x128 block tile, BK=32, 256 threads = 4 waves in 2x2, each wave 4x4
// grid of 16x16x32 MFMA tiles. global_load_lds width-16 staging.
// M,N multiples of 128; K multiple of 32.
// ---------------------------------------------------------------------------
__global__ __launch_bounds__(256) void gemm_bt_tanh(
    const ushort_t* __restrict__ A,
    const ushort_t* __restrict__ BT,
    const float* __restrict__ bias,
    ushort_t* __restrict__ C,
    int M, int N_, int K)
{
    __shared__ __align__(16) ushort_t sA[128 * 32];   // [row][k] 8 KB
    __shared__ __align__(16) ushort_t sB[128 * 32];   // [col][k] 8 KB

    const int t    = threadIdx.x;
    const int lane = t & 63;
    const int w    = t >> 6;         // wave 0..3
    const int wy   = w >> 1;         // wave row (0..1)
    const int wx   = w & 1;          // wave col (0..1)
    const int quad = lane >> 4;      // 0..3
    const int l16  = lane & 15;

    const int brow = blockIdx.y * 128;
    const int bcol = blockIdx.x * 128;

    f32x4 acc[4][4] = {};

    // staging: 512 16B-chunks per buffer; 2 per thread per buffer.
    // chunk c -> row c>>2, element offset (c&3)*8. Wave-uniform LDS base.
    const int cwb = (t & ~63);       // wave-uniform chunk base (pass 0)

    for (int k0 = 0; k0 < K; k0 += 32) {
        __syncthreads();             // previous iteration's LDS reads done
#pragma unroll
        for (int p = 0; p < 2; ++p) {
            const int c  = p * 256 + t;
            const int cb = p * 256 + cwb;
            const ushort_t* ga = A  + (size_t)(brow + (c >> 2)) * K + k0 + (c & 3) * 8;
            const ushort_t* gb = BT + (size_t)(bcol + (c >> 2)) * K + k0 + (c & 3) * 8;
            __builtin_amdgcn_global_load_lds(
                (const __attribute__((address_space(1))) void*)ga,
                (__attribute__((address_space(3))) void*)(sA + (size_t)cb * 8), 16, 0, 0);
            __builtin_amdgcn_global_load_lds(
                (const __attribute__((address_space(1))) void*)gb,
                (__attribute__((address_space(3))) void*)(sB + (size_t)cb * 8), 16, 0, 0);
        }
        __syncthreads();             // drains vmcnt before barrier

        bf16x8 af[4], bfr[4];
#pragma unroll
        for (int i = 0; i < 4; ++i) {
            af[i]  = *(const bf16x8*)(sA + (wy * 64 + i * 16 + l16) * 32 + quad * 8);
            bfr[i] = *(const bf16x8*)(sB + (wx * 64 + i * 16 + l16) * 32 + quad * 8);
        }
#pragma unroll
        for (int i = 0; i < 4; ++i)
#pragma unroll
            for (int j = 0; j < 4; ++j)
                acc[i][j] = __builtin_amdgcn_mfma_f32_16x16x32_bf16(
                    af[i], bfr[j], acc[i][j], 0, 0, 0);
    }

    // epilogue: C/D mapping col=lane&15, row=quad*4+reg  [m89/m91 verified]
    const int row0 = brow + wy * 64;
    const int col0 = bcol + wx * 64;
#pragma unroll
    for (int i = 0; i < 4; ++i) {
#pragma unroll
        for (int j = 0; j < 4; ++j) {
            const int col = col0 + j * 16 + l16;
            const float bv = bias[col];
#pragma unroll
            for (int r = 0; r < 4; ++r) {
                const int row = row0 + i * 16 + quad * 4 + r;
                C[(size_t)row * N_ + col] = f2bf(tanhf(acc[i][j][r] + bv));
            }
        }
    }
}

// ---------------------------------------------------------------------------
// Spline postprocess on one CHUNK of batch rows (net in bf16).
// blockIdx.x = local row, 512 threads = one spline unit each.
// ---------------------------------------------------------------------------
__global__ __launch_bounds__(512) void spline_post(
    const ushort_t* __restrict__ net,   // CHUNK x OUTD bf16
    const float* __restrict__ v_in,     // chunk rows x 2N
    const float* __restrict__ ld_in,    // chunk rows
    float* __restrict__ v_out,          // chunk rows x 2N
    float* __restrict__ ld_out)         // chunk rows
{
    const int b = blockIdx.x;
    const int n = threadIdx.x;          // 0..511

    const ushort_t* row = net + (size_t)b * OUTD + n * 17;
    float t17[17];
#pragma unroll
    for (int i = 0; i < 17; i++) t17[i] = bf2f(row[i]);

    // softmax over w_net = t17[9..16]
    float m = t17[9];
#pragma unroll
    for (int i = 10; i < 17; i++) m = fmaxf(m, t17[i]);
    float wn[8], wsum = 0.f;
#pragma unroll
    for (int i = 0; i < 8; i++) { wn[i] = expf(t17[9 + i] - m); wsum += wn[i]; }
    const float winv = 1.f / wsum;
#pragma unroll
    for (int i = 0; i < 8; i++) wn[i] *= winv;

    float eh[9];
#pragma unroll
    for (int i = 0; i < 9; i++) eh[i] = expf(t17[i]);
    float denom = 0.f;
#pragma unroll
    for (int k = 0; k < 8; k++) denom += 0.5f * wn[k] * (eh[k] + eh[k + 1]);
    const float dinv = 1.f / denom;
    float hn[9];
#pragma unroll
    for (int i = 0; i < 9; i++) hn[i] = eh[i] * dinv;

    float kx[9], ky[9];
    kx[0] = 0.f; ky[0] = 0.f;
#pragma unroll
    for (int k = 0; k < 8; k++) {
        kx[k + 1] = kx[k] + wn[k];
        ky[k + 1] = ky[k] + 0.5f * wn[k] * (hn[k] + hn[k + 1]);
    }

    const float va = v_in[(size_t)b * (2 * NN) + NN + n];

    int cnt = 0;
#pragma unroll
    for (int j = 0; j < 9; j++) cnt += (kx[j] < va) ? 1 : 0;
    int k = cnt - 1;
    k = k < 0 ? 0 : (k > KKN - 1 ? KKN - 1 : k);

    const float wseg = wn[k];
    const float hlo = hn[k], hhi = hn[k + 1];
    const float xlo = kx[k], ylo = ky[k];
    const float alpha = (va - xlo) / wseg;
    const float vact = ylo + alpha * hlo * wseg + 0.5f * alpha * alpha * (hhi - hlo) * wseg;
    const float lt = logf(hlo + alpha * (hhi - hlo));

    v_out[(size_t)b * (2 * NN) + n]      = v_in[(size_t)b * (2 * NN) + n];
    v_out[(size_t)b * (2 * NN) + NN + n] = vact;

    __shared__ float red[512];
    red[n] = lt;
    __syncthreads();
#pragma unroll
    for (int s = 256; s > 0; s >>= 1) {
        if (n < s) red[n] += red[n + s];
        __syncthreads();
    }
    if (n == 0) ld_out[b] = ld_in[b] - red[0];
}

// ---------------------------------------------------------------------------
extern "C" void kernel_launch(void* const* d_in, const int* in_sizes, int n_in,
                              void* d_out, int out_size, void* d_ws, size_t ws_size,
                              hipStream_t stream)
{
    const float* v_in = (const float*)d_in[0];   // B x 2N
    const float* ld   = (const float*)d_in[1];   // B x 1
    const float* W1   = (const float*)d_in[2];   // N x H
    const float* b1   = (const float*)d_in[3];   // H
    const float* W2   = (const float*)d_in[4];   // H x H
    const float* b2   = (const float*)d_in[5];   // H
    const float* W3   = (const float*)d_in[6];   // H x OUTD
    const float* b3   = (const float*)d_in[7];   // OUTD

    float* out    = (float*)d_out;
    float* v_out  = out;                           // B*2N
    float* ld_out = out + (size_t)BB * (2 * NN);   // B

    // workspace layout (bytes), total 60 MiB <= verified 64 MiB:
    //   [0,        8Mi)  a0b  : B x N bf16        (dead after GEMM1)
    //   [8Mi,     24Mi)  x1b  : B x H bf16        (dead after GEMM2)
    //   [24Mi,    40Mi)  x2b  : B x H bf16
    //   [40Mi,    41Mi)  W1T  : H x N bf16
    //   [41Mi,    43Mi)  W2T  : H x H bf16
    //   [43Mi,    60Mi)  W3T  : OUTD x H bf16
    //   chunkbuf (CHUNK x OUTD bf16 = 17 MiB) aliases [0, 17Mi) -- a0b+x1b,
    //   both dead by the time GEMM3 runs (stream order serializes hazards).
    char* ws = (char*)d_ws;
    const size_t Mi = 1024 * 1024;
    ushort_t* a0b = (ushort_t*)(ws);
    ushort_t* x1b = (ushort_t*)(ws + 8 * Mi);
    ushort_t* x2b = (ushort_t*)(ws + 24 * Mi);
    ushort_t* W1T = (ushort_t*)(ws + 40 * Mi);
    ushort_t* W2T = (ushort_t*)(ws + 41 * Mi);
    ushort_t* W3T = (ushort_t*)(ws + 43 * Mi);
    ushort_t* chunkbuf = (ushort_t*)(ws);

    // conversions
    conv_v<<<dim3(BB * NN / 2 / 256), dim3(256), 0, stream>>>(v_in, a0b);
    transpose_cvt<<<dim3(HH / 32, NN / 32),   dim3(32, 8), 0, stream>>>(W1, W1T, NN, HH);
    transpose_cvt<<<dim3(HH / 32, HH / 32),   dim3(32, 8), 0, stream>>>(W2, W2T, HH, HH);
    transpose_cvt<<<dim3(OUTD / 32, HH / 32), dim3(32, 8), 0, stream>>>(W3, W3T, HH, OUTD);

    // GEMM1: x1 = tanh((v_passive-0.5) @ W1 + b1)   M=8192 N=1024 K=512
    gemm_bt_tanh<<<dim3(HH / 128, BB / 128), dim3(256), 0, stream>>>(
        a0b, W1T, b1, x1b, BB, HH, NN);
    // GEMM2: x2 = tanh(x1 @ W2 + b2)                M=8192 N=1024 K=1024
    gemm_bt_tanh<<<dim3(HH / 128, BB / 128), dim3(256), 0, stream>>>(
        x1b, W2T, b2, x2b, BB, HH, HH);

    // GEMM3 + spline, chunked (CHUNK=1024 rows)
    for (int c = 0; c < BB / CHUNK; ++c) {
        const ushort_t* xa = x2b + (size_t)c * CHUNK * HH;
        gemm_bt_tanh<<<dim3(OUTD / 128, CHUNK / 128), dim3(256), 0, stream>>>(
            xa, W3T, b3, chunkbuf, CHUNK, OUTD, HH);
        spline_post<<<dim3(CHUNK), dim3(512), 0, stream>>>(
            chunkbuf,
            v_in   + (size_t)c * CHUNK * (2 * NN),
            ld     + (size_t)c * CHUNK,
            v_out  + (size_t)c * CHUNK * (2 * NN),
            ld_out + (size_t)c * CHUNK);
    }
}

// Round 4
// 444.906 us; speedup vs baseline: 6.6357x; 1.3045x over previous
//
#include <hip/hip_runtime.h>
#include <math.h>

// Problem constants
#define BB    8192
#define NN    512
#define KKN   8
#define HH    1024
#define OUTD  (NN * (2 * KKN + 1))   // 8704

typedef unsigned short ushort_t;
typedef __bf16 bf16x8 __attribute__((ext_vector_type(8)));
typedef float  f32x4  __attribute__((ext_vector_type(4)));

// float -> bf16 round-to-nearest-even
__device__ inline ushort_t f2bf(float f) {
    unsigned int u = __float_as_uint(f);
    unsigned int r = (u + 0x7fffu + ((u >> 16) & 1u)) >> 16;
    return (ushort_t)r;
}
__device__ inline float bf2f(ushort_t u) {
    return __uint_as_float(((unsigned int)u) << 16);
}

// ---------------------------------------------------------------------------
// conv_v: a0b[b][n] = bf16(v_in[b][n] - 0.5), n in [0,512). v_in rows are 1024.
// ---------------------------------------------------------------------------
__global__ __launch_bounds__(256) void conv_v(
    const float* __restrict__ v_in, ushort_t* __restrict__ a0b)
{
    int t = blockIdx.x * 256 + threadIdx.x;          // 0 .. B*512/2-1
    int e0 = t * 2;
    int b = e0 >> 9;
    int n = e0 & 511;
    const float2 v = *(const float2*)(v_in + (size_t)b * (2 * NN) + n);
    ushort_t* o = a0b + (size_t)b * NN + n;
    o[0] = f2bf(v.x - 0.5f);
    o[1] = f2bf(v.y - 0.5f);
}

// ---------------------------------------------------------------------------
// transpose_cvt: W (Kd x Nd fp32 row-major) -> WT (Nd x Kd bf16 row-major)
// ---------------------------------------------------------------------------
__global__ __launch_bounds__(256) void transpose_cvt(
    const float* __restrict__ W, ushort_t* __restrict__ WT, int Kd, int Nd)
{
    __shared__ float tile[32][33];
    const int bx = blockIdx.x * 32;   // n base
    const int by = blockIdx.y * 32;   // k base
    const int tx = threadIdx.x;       // 0..31
    const int ty = threadIdx.y;       // 0..7
#pragma unroll
    for (int i = 0; i < 32; i += 8)
        tile[ty + i][tx] = W[(size_t)(by + ty + i) * Nd + bx + tx];
    __syncthreads();
#pragma unroll
    for (int i = 0; i < 32; i += 8)
        WT[(size_t)(bx + ty + i) * Kd + by + tx] = f2bf(tile[tx][ty + i]);
}

// ---------------------------------------------------------------------------
// bf16 MFMA GEMM (m97 structure): C = bf16(tanh(A @ B + bias))
//   A : M x K bf16 row-major; BT: N x K bf16 row-major; C: M x N bf16.
// 128x128 tile, BK=32, 256 threads = 2x2 waves, 4x4 16x16x32 MFMAs per wave.
// ---------------------------------------------------------------------------
__global__ __launch_bounds__(256) void gemm_bt_tanh(
    const ushort_t* __restrict__ A,
    const ushort_t* __restrict__ BT,
    const float* __restrict__ bias,
    ushort_t* __restrict__ C,
    int M, int N_, int K)
{
    __shared__ __align__(16) ushort_t sA[128 * 32];   // [row][k] 8 KB
    __shared__ __align__(16) ushort_t sB[128 * 32];   // [col][k] 8 KB

    const int t    = threadIdx.x;
    const int lane = t & 63;
    const int w    = t >> 6;
    const int wy   = w >> 1;
    const int wx   = w & 1;
    const int quad = lane >> 4;
    const int l16  = lane & 15;

    const int brow = blockIdx.y * 128;
    const int bcol = blockIdx.x * 128;

    f32x4 acc[4][4] = {};

    const int cwb = (t & ~63);       // wave-uniform chunk base

    for (int k0 = 0; k0 < K; k0 += 32) {
        __syncthreads();
#pragma unroll
        for (int p = 0; p < 2; ++p) {
            const int c  = p * 256 + t;
            const int cb = p * 256 + cwb;
            const ushort_t* ga = A  + (size_t)(brow + (c >> 2)) * K + k0 + (c & 3) * 8;
            const ushort_t* gb = BT + (size_t)(bcol + (c >> 2)) * K + k0 + (c & 3) * 8;
            __builtin_amdgcn_global_load_lds(
                (const __attribute__((address_space(1))) void*)ga,
                (__attribute__((address_space(3))) void*)(sA + (size_t)cb * 8), 16, 0, 0);
            __builtin_amdgcn_global_load_lds(
                (const __attribute__((address_space(1))) void*)gb,
                (__attribute__((address_space(3))) void*)(sB + (size_t)cb * 8), 16, 0, 0);
        }
        __syncthreads();

        bf16x8 af[4], bfr[4];
#pragma unroll
        for (int i = 0; i < 4; ++i) {
            af[i]  = *(const bf16x8*)(sA + (wy * 64 + i * 16 + l16) * 32 + quad * 8);
            bfr[i] = *(const bf16x8*)(sB + (wx * 64 + i * 16 + l16) * 32 + quad * 8);
        }
#pragma unroll
        for (int i = 0; i < 4; ++i)
#pragma unroll
            for (int j = 0; j < 4; ++j)
                acc[i][j] = __builtin_amdgcn_mfma_f32_16x16x32_bf16(
                    af[i], bfr[j], acc[i][j], 0, 0, 0);
    }

    // epilogue: C/D mapping col=lane&15, row=quad*4+reg  [m89/m91 verified]
    const int row0 = brow + wy * 64;
    const int col0 = bcol + wx * 64;
#pragma unroll
    for (int i = 0; i < 4; ++i) {
#pragma unroll
        for (int j = 0; j < 4; ++j) {
            const int col = col0 + j * 16 + l16;
            const float bv = bias[col];
#pragma unroll
            for (int r = 0; r < 4; ++r) {
                const int row = row0 + i * 16 + quad * 4 + r;
                C[(size_t)row * N_ + col] = f2bf(tanhf(acc[i][j][r] + bv));
            }
        }
    }
}

// ---------------------------------------------------------------------------
// Spline postprocess. One block per batch row (local index within chunk),
// 512 threads = one spline unit each. Net row staged to LDS with coalesced
// float4 loads; log-term reduction via wave shuffle + 8 partials.
// ---------------------------------------------------------------------------
__global__ __launch_bounds__(512) void spline_post(
    const ushort_t* __restrict__ net,   // rows x OUTD bf16
    const float* __restrict__ v_in,     // rows x 2N
    const float* __restrict__ ld_in,    // rows
    float* __restrict__ v_out,          // rows x 2N
    float* __restrict__ ld_out)         // rows
{
    const int b = blockIdx.x;
    const int n = threadIdx.x;          // 0..511

    __shared__ __align__(16) ushort_t srow[OUTD];   // 17408 B
    __shared__ float wred[8];

    // coalesced stage: 1088 float4 chunks (17408 B, base is 16B-aligned
    // since OUTD*2 = 17408 is a multiple of 16)
    {
        const float4* g = (const float4*)(net + (size_t)b * OUTD);
        float4* s = (float4*)srow;
        for (int i = n; i < OUTD * 2 / 16; i += 512) s[i] = g[i];
    }
    __syncthreads();

    float t17[17];
#pragma unroll
    for (int i = 0; i < 17; i++) t17[i] = bf2f(srow[n * 17 + i]);

    // softmax over w_net = t17[9..16]
    float m = t17[9];
#pragma unroll
    for (int i = 10; i < 17; i++) m = fmaxf(m, t17[i]);
    float wn[8], wsum = 0.f;
#pragma unroll
    for (int i = 0; i < 8; i++) { wn[i] = expf(t17[9 + i] - m); wsum += wn[i]; }
    const float winv = 1.f / wsum;
#pragma unroll
    for (int i = 0; i < 8; i++) wn[i] *= winv;

    float eh[9];
#pragma unroll
    for (int i = 0; i < 9; i++) eh[i] = expf(t17[i]);
    float denom = 0.f;
#pragma unroll
    for (int k = 0; k < 8; k++) denom += 0.5f * wn[k] * (eh[k] + eh[k + 1]);
    const float dinv = 1.f / denom;
    float hn[9];
#pragma unroll
    for (int i = 0; i < 9; i++) hn[i] = eh[i] * dinv;

    float kx[9], ky[9];
    kx[0] = 0.f; ky[0] = 0.f;
#pragma unroll
    for (int k = 0; k < 8; k++) {
        kx[k + 1] = kx[k] + wn[k];
        ky[k + 1] = ky[k] + 0.5f * wn[k] * (hn[k] + hn[k + 1]);
    }

    const float va = v_in[(size_t)b * (2 * NN) + NN + n];

    int cnt = 0;
#pragma unroll
    for (int j = 0; j < 9; j++) cnt += (kx[j] < va) ? 1 : 0;
    int k = cnt - 1;
    k = k < 0 ? 0 : (k > KKN - 1 ? KKN - 1 : k);

    const float wseg = wn[k];
    const float hlo = hn[k], hhi = hn[k + 1];
    const float xlo = kx[k], ylo = ky[k];
    const float alpha = (va - xlo) / wseg;
    const float vact = ylo + alpha * hlo * wseg + 0.5f * alpha * alpha * (hhi - hlo) * wseg;
    float lt = logf(hlo + alpha * (hhi - hlo));

    v_out[(size_t)b * (2 * NN) + n]      = v_in[(size_t)b * (2 * NN) + n];
    v_out[(size_t)b * (2 * NN) + NN + n] = vact;

    // reduction: wave shuffle, then 8 partials
#pragma unroll
    for (int o = 32; o > 0; o >>= 1) lt += __shfl_down(lt, o, 64);
    if ((n & 63) == 0) wred[n >> 6] = lt;
    __syncthreads();
    if (n == 0) {
        float s = 0.f;
#pragma unroll
        for (int i = 0; i < 8; i++) s += wred[i];
        ld_out[b] = ld_in[b] - s;
    }
}

// ---------------------------------------------------------------------------
extern "C" void kernel_launch(void* const* d_in, const int* in_sizes, int n_in,
                              void* d_out, int out_size, void* d_ws, size_t ws_size,
                              hipStream_t stream)
{
    const float* v_in = (const float*)d_in[0];   // B x 2N
    const float* ld   = (const float*)d_in[1];   // B x 1
    const float* W1   = (const float*)d_in[2];   // N x H
    const float* b1   = (const float*)d_in[3];   // H
    const float* W2   = (const float*)d_in[4];   // H x H
    const float* b2   = (const float*)d_in[5];   // H
    const float* W3   = (const float*)d_in[6];   // H x OUTD
    const float* b3   = (const float*)d_in[7];   // OUTD

    float* out    = (float*)d_out;
    float* v_out  = out;                           // B*2N
    float* ld_out = out + (size_t)BB * (2 * NN);   // B

    // Workspace layout (all sizes exact MiB):
    //   [0, region)           chunk net buffer; a0b (8Mi) + x1b (16Mi) alias
    //                         here (dead before any GEMM3 runs)
    //   [region, +16Mi)       x2b : B x H bf16
    //   [.., +1Mi)            W1T : H x N bf16
    //   [.., +2Mi)            W2T : H x H bf16
    //   [.., +17Mi)           W3T : OUTD x H bf16
    // region = max(24Mi, CHUNK*OUTD*2). Totals: CHUNK=1024 -> 60Mi (verified
    // working in R2), 2048 -> 70Mi, 4096 -> 104Mi, 8192 (full) -> 172Mi.
    // Tier is picked from ws_size (constant per process -> graph-safe).
    const size_t Mi = 1048576;
    int    chunk;
    size_t region;
    if      (ws_size >= 172 * Mi) { chunk = 8192; region = 136 * Mi; }
    else if (ws_size >= 104 * Mi) { chunk = 4096; region =  68 * Mi; }
    else if (ws_size >=  70 * Mi) { chunk = 2048; region =  34 * Mi; }
    else                          { chunk = 1024; region =  24 * Mi; }

    char* ws = (char*)d_ws;
    ushort_t* a0b = (ushort_t*)(ws);
    ushort_t* x1b = (ushort_t*)(ws + 8 * Mi);
    ushort_t* netc = (ushort_t*)(ws);                       // chunk buffer
    ushort_t* x2b = (ushort_t*)(ws + region);
    ushort_t* W1T = (ushort_t*)(ws + region + 16 * Mi);
    ushort_t* W2T = (ushort_t*)(ws + region + 17 * Mi);
    ushort_t* W3T = (ushort_t*)(ws + region + 19 * Mi);

    // conversions
    conv_v<<<dim3(BB * NN / 2 / 256), dim3(256), 0, stream>>>(v_in, a0b);
    transpose_cvt<<<dim3(HH / 32, NN / 32),   dim3(32, 8), 0, stream>>>(W1, W1T, NN, HH);
    transpose_cvt<<<dim3(HH / 32, HH / 32),   dim3(32, 8), 0, stream>>>(W2, W2T, HH, HH);
    transpose_cvt<<<dim3(OUTD / 32, HH / 32), dim3(32, 8), 0, stream>>>(W3, W3T, HH, OUTD);

    // GEMM1: x1 = tanh((v_passive-0.5) @ W1 + b1)   M=8192 N=1024 K=512
    gemm_bt_tanh<<<dim3(HH / 128, BB / 128), dim3(256), 0, stream>>>(
        a0b, W1T, b1, x1b, BB, HH, NN);
    // GEMM2: x2 = tanh(x1 @ W2 + b2)                M=8192 N=1024 K=1024
    gemm_bt_tanh<<<dim3(HH / 128, BB / 128), dim3(256), 0, stream>>>(
        x1b, W2T, b2, x2b, BB, HH, HH);

    // GEMM3 + spline, chunked (single pass when chunk==8192)
    for (int c = 0; c < BB / chunk; ++c) {
        const ushort_t* xa = x2b + (size_t)c * chunk * HH;
        gemm_bt_tanh<<<dim3(OUTD / 128, chunk / 128), dim3(256), 0, stream>>>(
            xa, W3T, b3, netc, chunk, OUTD, HH);
        spline_post<<<dim3(chunk), dim3(512), 0, stream>>>(
            netc,
            v_in   + (size_t)c * chunk * (2 * NN),
            ld     + (size_t)c * chunk,
            v_out  + (size_t)c * chunk * (2 * NN),
            ld_out + (size_t)c * chunk);
    }
}

// Round 5
// 431.713 us; speedup vs baseline: 6.8385x; 1.0306x over previous
//
#include <hip/hip_runtime.h>
#include <math.h>

// Problem constants
#define BB    8192
#define NN    512
#define KKN   8
#define HH    1024
#define OUTD  (NN * (2 * KKN + 1))   // 8704

typedef unsigned short ushort_t;
typedef __bf16 bf16x8 __attribute__((ext_vector_type(8)));
typedef float  f32x4  __attribute__((ext_vector_type(4)));

// float -> bf16 round-to-nearest-even
__device__ inline ushort_t f2bf(float f) {
    unsigned int u = __float_as_uint(f);
    unsigned int r = (u + 0x7fffu + ((u >> 16) & 1u)) >> 16;
    return (ushort_t)r;
}
__device__ inline float bf2f(ushort_t u) {
    return __uint_as_float(((unsigned int)u) << 16);
}

// fast tanh: t=e^{2x}, (t-1)/(t+1) via v_exp_f32 + v_rcp_f32. |err| ~1e-5,
// far below bf16 rounding. Clamp +-10 avoids inf/inf.
__device__ inline float fast_tanh(float x) {
    float xc = fminf(fmaxf(x, -10.f), 10.f);
    float t  = __expf(2.f * xc);
    return (t - 1.f) * __builtin_amdgcn_rcpf(t + 1.f);
}

// ---------------------------------------------------------------------------
// conv_v: a0b[b][n] = bf16(v_in[b][n] - 0.5), n in [0,512). v_in rows are 1024.
// ---------------------------------------------------------------------------
__global__ __launch_bounds__(256) void conv_v(
    const float* __restrict__ v_in, ushort_t* __restrict__ a0b)
{
    int t = blockIdx.x * 256 + threadIdx.x;          // 0 .. B*512/2-1
    int e0 = t * 2;
    int b = e0 >> 9;
    int n = e0 & 511;
    const float2 v = *(const float2*)(v_in + (size_t)b * (2 * NN) + n);
    ushort_t* o = a0b + (size_t)b * NN + n;
    o[0] = f2bf(v.x - 0.5f);
    o[1] = f2bf(v.y - 0.5f);
}

// ---------------------------------------------------------------------------
// transpose_cvt: W (Kd x Nd fp32 row-major) -> WT (Nd x Kd bf16 row-major)
// PERM: out-row r is remapped to (r%17)*512 + r/17 (plane-major net layout)
// ---------------------------------------------------------------------------
template <bool PERM>
__global__ __launch_bounds__(256) void transpose_cvt(
    const float* __restrict__ W, ushort_t* __restrict__ WT, int Kd, int Nd)
{
    __shared__ float tile[32][33];
    const int bx = blockIdx.x * 32;   // n base
    const int by = blockIdx.y * 32;   // k base
    const int tx = threadIdx.x;       // 0..31
    const int ty = threadIdx.y;       // 0..7
#pragma unroll
    for (int i = 0; i < 32; i += 8)
        tile[ty + i][tx] = W[(size_t)(by + ty + i) * Nd + bx + tx];
    __syncthreads();
#pragma unroll
    for (int i = 0; i < 32; i += 8) {
        int r = bx + ty + i;
        if (PERM) r = (r % 17) * 512 + (r / 17);
        WT[(size_t)r * Kd + by + tx] = f2bf(tile[tx][ty + i]);
    }
}

// ---------------------------------------------------------------------------
// bf16 MFMA GEMM (m97 structure): C = bf16(tanh(A @ B + bias))
//   A : M x K bf16 row-major; BT: N x K bf16 row-major; C: M x N bf16.
// 128x128 tile, BK=32, 256 threads = 2x2 waves, 4x4 16x16x32 MFMAs per wave.
// PERM_BIAS: bias index mapped back through the plane permutation
// (col' = p*512+n  ->  orig = n*17+p).
// ---------------------------------------------------------------------------
template <bool PERM_BIAS>
__global__ __launch_bounds__(256) void gemm_bt_tanh(
    const ushort_t* __restrict__ A,
    const ushort_t* __restrict__ BT,
    const float* __restrict__ bias,
    ushort_t* __restrict__ C,
    int M, int N_, int K)
{
    __shared__ __align__(16) ushort_t sA[128 * 32];   // [row][k] 8 KB
    __shared__ __align__(16) ushort_t sB[128 * 32];   // [col][k] 8 KB

    const int t    = threadIdx.x;
    const int lane = t & 63;
    const int w    = t >> 6;
    const int wy   = w >> 1;
    const int wx   = w & 1;
    const int quad = lane >> 4;
    const int l16  = lane & 15;

    const int brow = blockIdx.y * 128;
    const int bcol = blockIdx.x * 128;

    f32x4 acc[4][4] = {};

    const int cwb = (t & ~63);       // wave-uniform chunk base

    for (int k0 = 0; k0 < K; k0 += 32) {
        __syncthreads();
#pragma unroll
        for (int p = 0; p < 2; ++p) {
            const int c  = p * 256 + t;
            const int cb = p * 256 + cwb;
            const ushort_t* ga = A  + (size_t)(brow + (c >> 2)) * K + k0 + (c & 3) * 8;
            const ushort_t* gb = BT + (size_t)(bcol + (c >> 2)) * K + k0 + (c & 3) * 8;
            __builtin_amdgcn_global_load_lds(
                (const __attribute__((address_space(1))) void*)ga,
                (__attribute__((address_space(3))) void*)(sA + (size_t)cb * 8), 16, 0, 0);
            __builtin_amdgcn_global_load_lds(
                (const __attribute__((address_space(1))) void*)gb,
                (__attribute__((address_space(3))) void*)(sB + (size_t)cb * 8), 16, 0, 0);
        }
        __syncthreads();

        bf16x8 af[4], bfr[4];
#pragma unroll
        for (int i = 0; i < 4; ++i) {
            af[i]  = *(const bf16x8*)(sA + (wy * 64 + i * 16 + l16) * 32 + quad * 8);
            bfr[i] = *(const bf16x8*)(sB + (wx * 64 + i * 16 + l16) * 32 + quad * 8);
        }
#pragma unroll
        for (int i = 0; i < 4; ++i)
#pragma unroll
            for (int j = 0; j < 4; ++j)
                acc[i][j] = __builtin_amdgcn_mfma_f32_16x16x32_bf16(
                    af[i], bfr[j], acc[i][j], 0, 0, 0);
    }

    // epilogue: C/D mapping col=lane&15, row=quad*4+reg  [m89/m91 verified]
    const int row0 = brow + wy * 64;
    const int col0 = bcol + wx * 64;
#pragma unroll
    for (int i = 0; i < 4; ++i) {
#pragma unroll
        for (int j = 0; j < 4; ++j) {
            const int col = col0 + j * 16 + l16;
            const int bidx = PERM_BIAS ? ((col & 511) * 17 + (col >> 9)) : col;
            const float bv = bias[bidx];
#pragma unroll
            for (int r = 0; r < 4; ++r) {
                const int row = row0 + i * 16 + quad * 4 + r;
                C[(size_t)row * N_ + col] = f2bf(fast_tanh(acc[i][j][r] + bv));
            }
        }
    }
}

// ---------------------------------------------------------------------------
// Spline postprocess, plane-major net layout: net[b][p*512 + n] holds value
// p of unit n (p<9: h_net, p>=9: w_net). One block per batch row, 256
// threads; thread t handles units 2t, 2t+1 via dword plane loads (coalesced).
// ---------------------------------------------------------------------------
__global__ __launch_bounds__(256) void spline_post(
    const ushort_t* __restrict__ net,   // rows x OUTD bf16, plane-major
    const float* __restrict__ v_in,     // rows x 2N
    const float* __restrict__ ld_in,    // rows
    float* __restrict__ v_out,          // rows x 2N
    float* __restrict__ ld_out)         // rows
{
    const int b = blockIdx.x;
    const int t = threadIdx.x;          // 0..255

    // 17 coalesced dword loads: planes p, units {2t, 2t+1}
    unsigned int pl[17];
    const ushort_t* base = net + (size_t)b * OUTD + 2 * t;
#pragma unroll
    for (int p = 0; p < 17; ++p)
        pl[p] = *(const unsigned int*)(base + p * 512);

    // passive copy (units 2t, 2t+1)
    {
        const float2 vp = *(const float2*)(v_in + (size_t)b * (2 * NN) + 2 * t);
        *(float2*)(v_out + (size_t)b * (2 * NN) + 2 * t) = vp;
    }
    const float2 va2 = *(const float2*)(v_in + (size_t)b * (2 * NN) + NN + 2 * t);

    float vact[2];
    float lt_sum = 0.f;
#pragma unroll 1
    for (int u = 0; u < 2; ++u) {
        const int sh = u * 16;
        float t17[17];
#pragma unroll
        for (int p = 0; p < 17; ++p)
            t17[p] = bf2f((ushort_t)(pl[p] >> sh));

        // softmax over w_net = t17[9..16]
        float m = t17[9];
#pragma unroll
        for (int i = 10; i < 17; i++) m = fmaxf(m, t17[i]);
        float wn[8], wsum = 0.f;
#pragma unroll
        for (int i = 0; i < 8; i++) { wn[i] = __expf(t17[9 + i] - m); wsum += wn[i]; }
        const float winv = 1.f / wsum;
#pragma unroll
        for (int i = 0; i < 8; i++) wn[i] *= winv;

        float eh[9];
#pragma unroll
        for (int i = 0; i < 9; i++) eh[i] = __expf(t17[i]);
        float denom = 0.f;
#pragma unroll
        for (int k = 0; k < 8; k++) denom += 0.5f * wn[k] * (eh[k] + eh[k + 1]);
        const float dinv = 1.f / denom;
        float hn[9];
#pragma unroll
        for (int i = 0; i < 9; i++) hn[i] = eh[i] * dinv;

        float kx[9], ky[9];
        kx[0] = 0.f; ky[0] = 0.f;
#pragma unroll
        for (int k = 0; k < 8; k++) {
            kx[k + 1] = kx[k] + wn[k];
            ky[k + 1] = ky[k] + 0.5f * wn[k] * (hn[k] + hn[k + 1]);
        }

        const float va = (u == 0) ? va2.x : va2.y;
        int cnt = 0;
#pragma unroll
        for (int j = 0; j < 9; j++) cnt += (kx[j] < va) ? 1 : 0;
        int k = cnt - 1;
        k = k < 0 ? 0 : (k > KKN - 1 ? KKN - 1 : k);

        const float wseg = wn[k];
        const float hlo = hn[k], hhi = hn[k + 1];
        const float xlo = kx[k], ylo = ky[k];
        const float alpha = (va - xlo) / wseg;
        vact[u] = ylo + alpha * hlo * wseg + 0.5f * alpha * alpha * (hhi - hlo) * wseg;
        lt_sum += logf(hlo + alpha * (hhi - hlo));
    }

    *(float2*)(v_out + (size_t)b * (2 * NN) + NN + 2 * t) = make_float2(vact[0], vact[1]);

    // reduce lt_sum across 256 threads (4 waves)
    __shared__ float wred[4];
#pragma unroll
    for (int o = 32; o > 0; o >>= 1) lt_sum += __shfl_down(lt_sum, o, 64);
    if ((t & 63) == 0) wred[t >> 6] = lt_sum;
    __syncthreads();
    if (t == 0)
        ld_out[b] = ld_in[b] - (wred[0] + wred[1] + wred[2] + wred[3]);
}

// ---------------------------------------------------------------------------
extern "C" void kernel_launch(void* const* d_in, const int* in_sizes, int n_in,
                              void* d_out, int out_size, void* d_ws, size_t ws_size,
                              hipStream_t stream)
{
    const float* v_in = (const float*)d_in[0];   // B x 2N
    const float* ld   = (const float*)d_in[1];   // B x 1
    const float* W1   = (const float*)d_in[2];   // N x H
    const float* b1   = (const float*)d_in[3];   // H
    const float* W2   = (const float*)d_in[4];   // H x H
    const float* b2   = (const float*)d_in[5];   // H
    const float* W3   = (const float*)d_in[6];   // H x OUTD
    const float* b3   = (const float*)d_in[7];   // OUTD

    float* out    = (float*)d_out;
    float* v_out  = out;                           // B*2N
    float* ld_out = out + (size_t)BB * (2 * NN);   // B

    // Workspace tiers (R3-verified: full tier 172Mi fits):
    //   [0, region)       chunk net buffer (plane-major); a0b + x1b alias here
    //   [region, +16Mi)   x2b ; then W1T (1Mi) W2T (2Mi) W3T (17Mi)
    const size_t Mi = 1048576;
    int    chunk;
    size_t region;
    if      (ws_size >= 172 * Mi) { chunk = 8192; region = 136 * Mi; }
    else if (ws_size >= 104 * Mi) { chunk = 4096; region =  68 * Mi; }
    else if (ws_size >=  70 * Mi) { chunk = 2048; region =  34 * Mi; }
    else                          { chunk = 1024; region =  24 * Mi; }

    char* ws = (char*)d_ws;
    ushort_t* a0b = (ushort_t*)(ws);
    ushort_t* x1b = (ushort_t*)(ws + 8 * Mi);
    ushort_t* netc = (ushort_t*)(ws);                       // chunk buffer
    ushort_t* x2b = (ushort_t*)(ws + region);
    ushort_t* W1T = (ushort_t*)(ws + region + 16 * Mi);
    ushort_t* W2T = (ushort_t*)(ws + region + 17 * Mi);
    ushort_t* W3T = (ushort_t*)(ws + region + 19 * Mi);

    // conversions
    conv_v<<<dim3(BB * NN / 2 / 256), dim3(256), 0, stream>>>(v_in, a0b);
    transpose_cvt<false><<<dim3(HH / 32, NN / 32),   dim3(32, 8), 0, stream>>>(W1, W1T, NN, HH);
    transpose_cvt<false><<<dim3(HH / 32, HH / 32),   dim3(32, 8), 0, stream>>>(W2, W2T, HH, HH);
    transpose_cvt<true ><<<dim3(OUTD / 32, HH / 32), dim3(32, 8), 0, stream>>>(W3, W3T, HH, OUTD);

    // GEMM1: x1 = tanh((v_passive-0.5) @ W1 + b1)   M=8192 N=1024 K=512
    gemm_bt_tanh<false><<<dim3(HH / 128, BB / 128), dim3(256), 0, stream>>>(
        a0b, W1T, b1, x1b, BB, HH, NN);
    // GEMM2: x2 = tanh(x1 @ W2 + b2)                M=8192 N=1024 K=1024
    gemm_bt_tanh<false><<<dim3(HH / 128, BB / 128), dim3(256), 0, stream>>>(
        x1b, W2T, b2, x2b, BB, HH, HH);

    // GEMM3 + spline, chunked (single pass when chunk==8192)
    for (int c = 0; c < BB / chunk; ++c) {
        const ushort_t* xa = x2b + (size_t)c * chunk * HH;
        gemm_bt_tanh<true><<<dim3(OUTD / 128, chunk / 128), dim3(256), 0, stream>>>(
            xa, W3T, b3, netc, chunk, OUTD, HH);
        spline_post<<<dim3(chunk), dim3(256), 0, stream>>>(
            netc,
            v_in   + (size_t)c * chunk * (2 * NN),
            ld     + (size_t)c * chunk,
            v_out  + (size_t)c * chunk * (2 * NN),
            ld_out + (size_t)c * chunk);
    }
}

// Round 6
// 413.458 us; speedup vs baseline: 7.1405x; 1.0442x over previous
//
#include <hip/hip_runtime.h>
#include <math.h>

// Problem constants
#define BB    8192
#define NN    512
#define KKN   8
#define HH    1024
#define OUTD  (NN * (2 * KKN + 1))   // 8704

typedef unsigned short ushort_t;
typedef __bf16 bf16x8 __attribute__((ext_vector_type(8)));
typedef float  f32x4  __attribute__((ext_vector_type(4)));

// float -> bf16 round-to-nearest-even
__device__ inline ushort_t f2bf(float f) {
    unsigned int u = __float_as_uint(f);
    unsigned int r = (u + 0x7fffu + ((u >> 16) & 1u)) >> 16;
    return (ushort_t)r;
}
__device__ inline float bf2f(ushort_t u) {
    return __uint_as_float(((unsigned int)u) << 16);
}

// 5-op tanh: 1 - 2/(e^{2x}+1). Saturates correctly for |x| large
// (t=inf -> rcp=0 -> 1 ; t=0 -> 1-2 = -1). |err| ~1e-5 << bf16 ulp.
__device__ inline float fast_tanh(float x) {
    float t = __expf(x + x);
    return fmaf(-2.f, __builtin_amdgcn_rcpf(t + 1.f), 1.f);
}

// ---------------------------------------------------------------------------
// conv_v: a0b[b][n] = bf16(v_in[b][n] - 0.5), n in [0,512). v_in rows are 1024.
// ---------------------------------------------------------------------------
__global__ __launch_bounds__(256) void conv_v(
    const float* __restrict__ v_in, ushort_t* __restrict__ a0b)
{
    int t = blockIdx.x * 256 + threadIdx.x;          // 0 .. B*512/2-1
    int e0 = t * 2;
    int b = e0 >> 9;
    int n = e0 & 511;
    const float2 v = *(const float2*)(v_in + (size_t)b * (2 * NN) + n);
    ushort_t* o = a0b + (size_t)b * NN + n;
    o[0] = f2bf(v.x - 0.5f);
    o[1] = f2bf(v.y - 0.5f);
}

// ---------------------------------------------------------------------------
// transpose_cvt: W (Kd x Nd fp32 row-major) -> WT (Nd x Kd bf16 row-major)
// PERM: out-row r is remapped to (r%17)*512 + r/17 (plane-major net layout)
// ---------------------------------------------------------------------------
template <bool PERM>
__global__ __launch_bounds__(256) void transpose_cvt(
    const float* __restrict__ W, ushort_t* __restrict__ WT, int Kd, int Nd)
{
    __shared__ float tile[32][33];
    const int bx = blockIdx.x * 32;   // n base
    const int by = blockIdx.y * 32;   // k base
    const int tx = threadIdx.x;       // 0..31
    const int ty = threadIdx.y;       // 0..7
#pragma unroll
    for (int i = 0; i < 32; i += 8)
        tile[ty + i][tx] = W[(size_t)(by + ty + i) * Nd + bx + tx];
    __syncthreads();
#pragma unroll
    for (int i = 0; i < 32; i += 8) {
        int r = bx + ty + i;
        if (PERM) r = (r % 17) * 512 + (r / 17);
        WT[(size_t)r * Kd + by + tx] = f2bf(tile[tx][ty + i]);
    }
}

// ---------------------------------------------------------------------------
// bf16 MFMA GEMM (m97 structure + bank-conflict swizzle):
//   C = bf16(tanh(A @ B + bias))
//   A : M x K bf16 row-major; BT: N x K bf16 row-major; C: M x N bf16.
// 128x128 tile, BK=32, 256 threads = 2x2 waves, 4x4 16x16x32 MFMAs per wave.
//
// LDS swizzle: row r's k-chunk g (16B) is stored at slot-pos (g+(r>>1))&3.
// global_load_lds forces dest = base + lane*16, so the swizzle is applied by
// permuting WHICH global chunk each lane fetches (same address set -> same
// coalescing). Fragment read offset uses (quad+(row>>1))&3: a 16-lane read
// phase then hits each bank-group exactly 2x (2-way = free, m136) instead of
// the unswizzled 8-way.
// ---------------------------------------------------------------------------
template <bool PERM_BIAS>
__global__ __launch_bounds__(256) void gemm_bt_tanh(
    const ushort_t* __restrict__ A,
    const ushort_t* __restrict__ BT,
    const float* __restrict__ bias,
    ushort_t* __restrict__ C,
    int M, int N_, int K)
{
    __shared__ __align__(16) ushort_t sA[128 * 32];   // [row][k-chunk swizzled] 8 KB
    __shared__ __align__(16) ushort_t sB[128 * 32];

    const int t    = threadIdx.x;
    const int lane = t & 63;
    const int w    = t >> 6;
    const int wy   = w >> 1;
    const int wx   = w & 1;
    const int quad = lane >> 4;
    const int l16  = lane & 15;

    const int brow = blockIdx.y * 128;
    const int bcol = blockIdx.x * 128;

    f32x4 acc[4][4] = {};

    const int cwb = (t & ~63);       // wave-uniform chunk base

    // staging: slot c = p*256 + t holds (row r = c>>2, k-chunk g = ((c&3)-(r>>1))&3)
    int rS[2], gS[2];
#pragma unroll
    for (int p = 0; p < 2; ++p) {
        const int c = p * 256 + t;
        rS[p] = c >> 2;
        gS[p] = ((c & 3) - (rS[p] >> 1)) & 3;
    }

    // fragment LDS byte-offsets (k0-invariant)
    int offA[4], offB[4];
#pragma unroll
    for (int i = 0; i < 4; ++i) {
        const int rowA = wy * 64 + i * 16 + l16;
        offA[i] = rowA * 32 + ((quad + (rowA >> 1)) & 3) * 8;
        const int rowB = wx * 64 + i * 16 + l16;
        offB[i] = rowB * 32 + ((quad + (rowB >> 1)) & 3) * 8;
    }

    for (int k0 = 0; k0 < K; k0 += 32) {
        __syncthreads();
#pragma unroll
        for (int p = 0; p < 2; ++p) {
            const int cb = p * 256 + cwb;
            const ushort_t* ga = A  + (size_t)(brow + rS[p]) * K + k0 + gS[p] * 8;
            const ushort_t* gb = BT + (size_t)(bcol + rS[p]) * K + k0 + gS[p] * 8;
            __builtin_amdgcn_global_load_lds(
                (const __attribute__((address_space(1))) void*)ga,
                (__attribute__((address_space(3))) void*)(sA + (size_t)cb * 8), 16, 0, 0);
            __builtin_amdgcn_global_load_lds(
                (const __attribute__((address_space(1))) void*)gb,
                (__attribute__((address_space(3))) void*)(sB + (size_t)cb * 8), 16, 0, 0);
        }
        __syncthreads();

        bf16x8 af[4], bfr[4];
#pragma unroll
        for (int i = 0; i < 4; ++i) {
            af[i]  = *(const bf16x8*)(sA + offA[i]);
            bfr[i] = *(const bf16x8*)(sB + offB[i]);
        }
#pragma unroll
        for (int i = 0; i < 4; ++i)
#pragma unroll
            for (int j = 0; j < 4; ++j)
                acc[i][j] = __builtin_amdgcn_mfma_f32_16x16x32_bf16(
                    af[i], bfr[j], acc[i][j], 0, 0, 0);
    }

    // epilogue: C/D mapping col=lane&15, row=quad*4+reg  [m89/m91 verified]
    const int row0 = brow + wy * 64;
    const int col0 = bcol + wx * 64;
#pragma unroll
    for (int i = 0; i < 4; ++i) {
#pragma unroll
        for (int j = 0; j < 4; ++j) {
            const int col = col0 + j * 16 + l16;
            const int bidx = PERM_BIAS ? ((col & 511) * 17 + (col >> 9)) : col;
            const float bv = bias[bidx];
#pragma unroll
            for (int r = 0; r < 4; ++r) {
                const int row = row0 + i * 16 + quad * 4 + r;
                C[(size_t)row * N_ + col] = f2bf(fast_tanh(acc[i][j][r] + bv));
            }
        }
    }
}

// ---------------------------------------------------------------------------
// Spline postprocess, plane-major net layout: net[b][p*512 + n] holds value
// p of unit n (p<9: h_net, p>=9: w_net). One block per batch row, 256
// threads; thread t handles units 2t, 2t+1 via dword plane loads (coalesced).
// ---------------------------------------------------------------------------
__global__ __launch_bounds__(256) void spline_post(
    const ushort_t* __restrict__ net,   // rows x OUTD bf16, plane-major
    const float* __restrict__ v_in,     // rows x 2N
    const float* __restrict__ ld_in,    // rows
    float* __restrict__ v_out,          // rows x 2N
    float* __restrict__ ld_out)         // rows
{
    const int b = blockIdx.x;
    const int t = threadIdx.x;          // 0..255

    // 17 coalesced dword loads: planes p, units {2t, 2t+1}
    unsigned int pl[17];
    const ushort_t* base = net + (size_t)b * OUTD + 2 * t;
#pragma unroll
    for (int p = 0; p < 17; ++p)
        pl[p] = *(const unsigned int*)(base + p * 512);

    // passive copy (units 2t, 2t+1)
    {
        const float2 vp = *(const float2*)(v_in + (size_t)b * (2 * NN) + 2 * t);
        *(float2*)(v_out + (size_t)b * (2 * NN) + 2 * t) = vp;
    }
    const float2 va2 = *(const float2*)(v_in + (size_t)b * (2 * NN) + NN + 2 * t);

    float vact[2];
    float lt_sum = 0.f;
#pragma unroll 1
    for (int u = 0; u < 2; ++u) {
        const int sh = u * 16;
        float t17[17];
#pragma unroll
        for (int p = 0; p < 17; ++p)
            t17[p] = bf2f((ushort_t)(pl[p] >> sh));

        // softmax over w_net = t17[9..16]
        float m = t17[9];
#pragma unroll
        for (int i = 10; i < 17; i++) m = fmaxf(m, t17[i]);
        float wn[8], wsum = 0.f;
#pragma unroll
        for (int i = 0; i < 8; i++) { wn[i] = __expf(t17[9 + i] - m); wsum += wn[i]; }
        const float winv = 1.f / wsum;
#pragma unroll
        for (int i = 0; i < 8; i++) wn[i] *= winv;

        float eh[9];
#pragma unroll
        for (int i = 0; i < 9; i++) eh[i] = __expf(t17[i]);
        float denom = 0.f;
#pragma unroll
        for (int k = 0; k < 8; k++) denom += 0.5f * wn[k] * (eh[k] + eh[k + 1]);
        const float dinv = 1.f / denom;
        float hn[9];
#pragma unroll
        for (int i = 0; i < 9; i++) hn[i] = eh[i] * dinv;

        float kx[9], ky[9];
        kx[0] = 0.f; ky[0] = 0.f;
#pragma unroll
        for (int k = 0; k < 8; k++) {
            kx[k + 1] = kx[k] + wn[k];
            ky[k + 1] = ky[k] + 0.5f * wn[k] * (hn[k] + hn[k + 1]);
        }

        const float va = (u == 0) ? va2.x : va2.y;
        int cnt = 0;
#pragma unroll
        for (int j = 0; j < 9; j++) cnt += (kx[j] < va) ? 1 : 0;
        int k = cnt - 1;
        k = k < 0 ? 0 : (k > KKN - 1 ? KKN - 1 : k);

        const float wseg = wn[k];
        const float hlo = hn[k], hhi = hn[k + 1];
        const float xlo = kx[k], ylo = ky[k];
        const float alpha = (va - xlo) / wseg;
        vact[u] = ylo + alpha * hlo * wseg + 0.5f * alpha * alpha * (hhi - hlo) * wseg;
        lt_sum += __logf(hlo + alpha * (hhi - hlo));
    }

    *(float2*)(v_out + (size_t)b * (2 * NN) + NN + 2 * t) = make_float2(vact[0], vact[1]);

    // reduce lt_sum across 256 threads (4 waves)
    __shared__ float wred[4];
#pragma unroll
    for (int o = 32; o > 0; o >>= 1) lt_sum += __shfl_down(lt_sum, o, 64);
    if ((t & 63) == 0) wred[t >> 6] = lt_sum;
    __syncthreads();
    if (t == 0)
        ld_out[b] = ld_in[b] - (wred[0] + wred[1] + wred[2] + wred[3]);
}

// ---------------------------------------------------------------------------
extern "C" void kernel_launch(void* const* d_in, const int* in_sizes, int n_in,
                              void* d_out, int out_size, void* d_ws, size_t ws_size,
                              hipStream_t stream)
{
    const float* v_in = (const float*)d_in[0];   // B x 2N
    const float* ld   = (const float*)d_in[1];   // B x 1
    const float* W1   = (const float*)d_in[2];   // N x H
    const float* b1   = (const float*)d_in[3];   // H
    const float* W2   = (const float*)d_in[4];   // H x H
    const float* b2   = (const float*)d_in[5];   // H
    const float* W3   = (const float*)d_in[6];   // H x OUTD
    const float* b3   = (const float*)d_in[7];   // OUTD

    float* out    = (float*)d_out;
    float* v_out  = out;                           // B*2N
    float* ld_out = out + (size_t)BB * (2 * NN);   // B

    // Workspace tiers (R3-verified: full tier 172Mi fits):
    //   [0, region)       chunk net buffer (plane-major); a0b + x1b alias here
    //   [region, +16Mi)   x2b ; then W1T (1Mi) W2T (2Mi) W3T (17Mi)
    const size_t Mi = 1048576;
    int    chunk;
    size_t region;
    if      (ws_size >= 172 * Mi) { chunk = 8192; region = 136 * Mi; }
    else if (ws_size >= 104 * Mi) { chunk = 4096; region =  68 * Mi; }
    else if (ws_size >=  70 * Mi) { chunk = 2048; region =  34 * Mi; }
    else                          { chunk = 1024; region =  24 * Mi; }

    char* ws = (char*)d_ws;
    ushort_t* a0b = (ushort_t*)(ws);
    ushort_t* x1b = (ushort_t*)(ws + 8 * Mi);
    ushort_t* netc = (ushort_t*)(ws);                       // chunk buffer
    ushort_t* x2b = (ushort_t*)(ws + region);
    ushort_t* W1T = (ushort_t*)(ws + region + 16 * Mi);
    ushort_t* W2T = (ushort_t*)(ws + region + 17 * Mi);
    ushort_t* W3T = (ushort_t*)(ws + region + 19 * Mi);

    // conversions
    conv_v<<<dim3(BB * NN / 2 / 256), dim3(256), 0, stream>>>(v_in, a0b);
    transpose_cvt<false><<<dim3(HH / 32, NN / 32),   dim3(32, 8), 0, stream>>>(W1, W1T, NN, HH);
    transpose_cvt<false><<<dim3(HH / 32, HH / 32),   dim3(32, 8), 0, stream>>>(W2, W2T, HH, HH);
    transpose_cvt<true ><<<dim3(OUTD / 32, HH / 32), dim3(32, 8), 0, stream>>>(W3, W3T, HH, OUTD);

    // GEMM1: x1 = tanh((v_passive-0.5) @ W1 + b1)   M=8192 N=1024 K=512
    gemm_bt_tanh<false><<<dim3(HH / 128, BB / 128), dim3(256), 0, stream>>>(
        a0b, W1T, b1, x1b, BB, HH, NN);
    // GEMM2: x2 = tanh(x1 @ W2 + b2)                M=8192 N=1024 K=1024
    gemm_bt_tanh<false><<<dim3(HH / 128, BB / 128), dim3(256), 0, stream>>>(
        x1b, W2T, b2, x2b, BB, HH, HH);

    // GEMM3 + spline, chunked (single pass when chunk==8192)
    for (int c = 0; c < BB / chunk; ++c) {
        const ushort_t* xa = x2b + (size_t)c * chunk * HH;
        gemm_bt_tanh<true><<<dim3(OUTD / 128, chunk / 128), dim3(256), 0, stream>>>(
            xa, W3T, b3, netc, chunk, OUTD, HH);
        spline_post<<<dim3(chunk), dim3(256), 0, stream>>>(
            netc,
            v_in   + (size_t)c * chunk * (2 * NN),
            ld     + (size_t)c * chunk,
            v_out  + (size_t)c * chunk * (2 * NN),
            ld_out + (size_t)c * chunk);
    }
}